// Round 10
// baseline (259.944 us; speedup 1.0000x reference)
//
#include <hip/hip_runtime.h>
#include <cstdint>
#include <cstddef>

#define Bdim 4
#define Tdim 2048
#define Cdim 1024

// scan geometry: block 1024 = CHB(32) channels x SEG(32) segments of LSEG(64)
#define SEG  32
#define CHB  32
#define LSEG (Tdim / SEG)

#define G1_K   1024
#define G1_N   6144
#define G1_NKT 32         // K-tiles of 32
#define G1_GXT 48         // N tiles (6144/128)
#define G1_NWG 1536       // 48 x 32

typedef __attribute__((ext_vector_type(8))) short bf16x8;
typedef __attribute__((ext_vector_type(4))) float f32x4;

__device__ __forceinline__ unsigned short f2bf(float f) {
    unsigned int u = __float_as_uint(f);
    u += 0x7fffu + ((u >> 16) & 1u);
    return (unsigned short)(u >> 16);
}
__device__ __forceinline__ float bf2f(unsigned short h) {
    return __uint_as_float((unsigned int)h << 16);
}

__device__ __forceinline__ void gload_lds16(const void* g, void* l) {
    __builtin_amdgcn_global_load_lds(
        (const __attribute__((address_space(1))) unsigned int*)g,
        (__attribute__((address_space(3))) unsigned int*)l,
        16, 0, 0);
}

// ---------------------------------------------------------------------------
// merged fp32 -> bf16 cast of x (8.4M), rkv_w (6.3M), out_w (2.1M)
// ---------------------------------------------------------------------------
__global__ __launch_bounds__(256) void cast_all(
    const float* __restrict__ x,  unsigned short* __restrict__ xb,  int n1,
    const float* __restrict__ w1, unsigned short* __restrict__ wb,  int n2,
    const float* __restrict__ w2, unsigned short* __restrict__ ob,  int n3)
{
    int i = blockIdx.x * 256 + threadIdx.x;
    const float* in; unsigned short* out;
    if (i < n1)           { in = x;  out = xb; }
    else if (i < n1 + n2) { in = w1; out = wb; i -= n1; }
    else if (i < n1 + n2 + n3) { in = w2; out = ob; i -= n1 + n2; }
    else return;
    float4 v = ((const float4*)in)[i];
    ushort4 o;
    o.x = f2bf(v.x); o.y = f2bf(v.y); o.z = f2bf(v.z); o.w = f2bf(v.w);
    ((ushort4*)out)[i] = o;
}

// ---------------------------------------------------------------------------
// GEMM1: 256(M) x 128(N) tile, BK=32, bf16 in/out, NT.
// 512 thr = 8 waves (4M x 2N), per-wave 64x64 output (4x4 16x16 frags).
// LDS: 3-slot rotation, A slots 3x16KB @0, B slots 3x8KB @49152 = 72KB
// -> 2 blocks/CU co-resident; the two blocks run phase-shifted, so one
// block's LDS-read burst overlaps the other's MFMA burst (m114 mechanism)
// without relying on compiler waitcnt placement.
//
// Phase t (t = ktile index): read frags from slot t%3; stage ktile t+2
// into slot (t+2)%3; barrier; 16 MFMA; vmcnt(3); barrier.
// Slot safety: slot (t+2)%3 == slot (t-1)%3, whose reads completed before
// phase t-1's MFMA (implicit lgkm wait) and t's stage issues after t-1's
// end barrier (no WAR). Slot t%3's data (staged at t-2, 3 loads/phase) is
// confirmed by vmcnt(3) at end of t-1 (outstanding = t-1's own 3 stage
// loads only => everything older, incl. t's data, retired) + barrier.
// Prologue: stage kt0->slot0, kt1->slot1, vmcnt(3) (kt0 confirmed), barrier.
// Tail: stage target clamped to kt31 (redundant loads into dead slots, safe).
// MFMA k-order identical to R9 => bit-identical output.
// ---------------------------------------------------------------------------
__device__ __forceinline__ void stage_128(
    const unsigned short* __restrict__ G, int row0, int K, int elemoff,
    char* slot, int wave, int lane)
{
    const int sl = (lane & 3) ^ ((lane >> 3) & 3);   // pre-swizzled source chunk
    const unsigned short* gp = G + (size_t)(row0 + wave * 16 + (lane >> 2)) * K
                                 + elemoff + sl * 8;
    gload_lds16(gp, slot + wave * 1024);
}

__global__ __launch_bounds__(512, 4) void gemm1_3slot(
    const unsigned short* __restrict__ A, const unsigned short* __restrict__ B,
    unsigned short* __restrict__ C)
{
    __shared__ char ldsb[73728];

    const int tid  = threadIdx.x;
    const int wave = tid >> 6;
    const int lane = tid & 63;
    const int wm = wave >> 1;          // 0..3 (M dir, 64 rows each)
    const int wn = wave & 1;           // 0..1 (N dir, 64 cols each)
    const int fr = lane & 15;
    const int cswz = (((lane >> 4) ^ ((fr >> 1) & 3)) << 4);

    // XCD swizzle (1536 % 8 == 0); N-major within chunk for A-panel L2 reuse
    const int swz = (blockIdx.x & 7) * (G1_NWG >> 3) + (blockIdx.x >> 3);
    const int bx  = swz % G1_GXT;
    const int by  = swz / G1_GXT;
    const int m0 = by * 256;
    const int n0 = bx * 128;

    f32x4 acc[4][4] = {};

    // prologue: kt0 -> slot0, kt1 -> slot1 (3 loads each)
    stage_128(A, m0,       G1_K, 0,  ldsb + 0,            wave, lane);
    stage_128(A, m0 + 128, G1_K, 0,  ldsb + 8192,         wave, lane);
    stage_128(B, n0,       G1_K, 0,  ldsb + 49152,        wave, lane);
    stage_128(A, m0,       G1_K, 32, ldsb + 16384,        wave, lane);
    stage_128(A, m0 + 128, G1_K, 32, ldsb + 16384 + 8192, wave, lane);
    stage_128(B, n0,       G1_K, 32, ldsb + 49152 + 8192, wave, lane);
    asm volatile("s_waitcnt vmcnt(3)" ::: "memory");   // kt0 slots arrived
    __builtin_amdgcn_s_barrier();
    __builtin_amdgcn_sched_barrier(0);

    int sR = 0;                         // read slot = t % 3
    for (int t = 0; t < G1_NKT; ++t) {
        const int sW = (sR >= 1) ? sR - 1 : 2;      // (t+2) % 3
        int kst = t + 2; if (kst > G1_NKT - 1) kst = G1_NKT - 1;
        const int keoff = kst * 32;

        const char* Asl = ldsb + sR * 16384;
        const char* Bsl = ldsb + 49152 + sR * 8192;

        bf16x8 af[4], bq[4];
        #pragma unroll
        for (int i_ = 0; i_ < 4; ++i_)
            af[i_] = *(const bf16x8*)(Asl + (wm * 64 + i_ * 16 + fr) * 64 + cswz);
        #pragma unroll
        for (int j_ = 0; j_ < 4; ++j_)
            bq[j_] = *(const bf16x8*)(Bsl + (wn * 64 + j_ * 16 + fr) * 64 + cswz);

        stage_128(A, m0,       G1_K, keoff, ldsb + sW * 16384,        wave, lane);
        stage_128(A, m0 + 128, G1_K, keoff, ldsb + sW * 16384 + 8192, wave, lane);
        stage_128(B, n0,       G1_K, keoff, ldsb + 49152 + sW * 8192, wave, lane);

        __builtin_amdgcn_s_barrier();
        __builtin_amdgcn_sched_barrier(0);
        __builtin_amdgcn_s_setprio(1);
        #pragma unroll
        for (int i_ = 0; i_ < 4; ++i_)
            #pragma unroll
            for (int j_ = 0; j_ < 4; ++j_)
                acc[i_][j_] = __builtin_amdgcn_mfma_f32_16x16x32_bf16(
                    af[i_], bq[j_], acc[i_][j_], 0, 0, 0);
        __builtin_amdgcn_s_setprio(0);
        asm volatile("s_waitcnt vmcnt(3)" ::: "memory");
        __builtin_amdgcn_s_barrier();
        __builtin_amdgcn_sched_barrier(0);

        sR = (sR < 2) ? sR + 1 : 0;
    }

    // epilogue: C/D layout col = lane&15, row = (lane>>4)*4 + reg
    #pragma unroll
    for (int i_ = 0; i_ < 4; ++i_) {
        const int row = m0 + wm * 64 + i_ * 16 + (lane >> 4) * 4;
        #pragma unroll
        for (int j_ = 0; j_ < 4; ++j_) {
            const int col = n0 + wn * 64 + j_ * 16 + fr;
            #pragma unroll
            for (int r = 0; r < 4; ++r)
                C[(size_t)(row + r) * G1_N + col] = f2bf(acc[i_][j_][r]);
        }
    }
}

// ---------------------------------------------------------------------------
// m97-structure 128x128 bf16 GEMM (NT), fp32 out — GEMM2 (grid 512).
// ---------------------------------------------------------------------------
__global__ __launch_bounds__(256) void gemm_bf16_nt(
    const unsigned short* __restrict__ A, const unsigned short* __restrict__ B,
    float* __restrict__ C, int M, int N, int K)
{
    __shared__ unsigned short As[128 * 32];
    __shared__ unsigned short Bs[128 * 32];

    const int tid  = threadIdx.x;
    const int wave = tid >> 6;
    const int lane = tid & 63;
    const int m0 = blockIdx.y * 128;
    const int n0 = blockIdx.x * 128;
    const int wr = wave >> 1, wc = wave & 1;

    const int srow = tid >> 2;
    const int scol = (tid & 3) * 8;
    const unsigned short* Ag = A + (size_t)(m0 + srow) * K + scol;
    const unsigned short* Bg = B + (size_t)(n0 + srow) * K + scol;
    char* AsW = (char*)As + wave * 1024;
    char* BsW = (char*)Bs + wave * 1024;

    f32x4 acc[4][4] = {};

    const int fr = lane & 15;
    const int fk = (lane >> 4) * 8;

    for (int k0 = 0; k0 < K; k0 += 32) {
        gload_lds16(Ag + k0,                  AsW);
        gload_lds16(Ag + k0 + (size_t)64 * K, AsW + 4096);
        gload_lds16(Bg + k0,                  BsW);
        gload_lds16(Bg + k0 + (size_t)64 * K, BsW + 4096);
        __syncthreads();

        bf16x8 af[4], bfr_[4];
        #pragma unroll
        for (int f = 0; f < 4; ++f) {
            af[f]   = *(const bf16x8*)&As[(wr * 64 + f * 16 + fr) * 32 + fk];
            bfr_[f] = *(const bf16x8*)&Bs[(wc * 64 + f * 16 + fr) * 32 + fk];
        }
        #pragma unroll
        for (int i = 0; i < 4; ++i)
            #pragma unroll
            for (int j = 0; j < 4; ++j)
                acc[i][j] = __builtin_amdgcn_mfma_f32_16x16x32_bf16(
                    af[i], bfr_[j], acc[i][j], 0, 0, 0);
        __syncthreads();
    }

    #pragma unroll
    for (int i = 0; i < 4; ++i) {
        const int row = m0 + wr * 64 + i * 16 + (lane >> 4) * 4;
        #pragma unroll
        for (int j = 0; j < 4; ++j) {
            const int col = n0 + wc * 64 + j * 16 + (lane & 15);
            #pragma unroll
            for (int r = 0; r < 4; ++r)
                C[(size_t)(row + r) * N + col] = acc[i][j][r];
        }
    }
}

// ---------------------------------------------------------------------------
// Segmented-parallel fused sigmoid(r)*WKV scan, bf16 in / bf16 out.
// Block = 1024 thr = CHB(32) x SEG(32), LSEG=64, PF=8. fp32 state.
// ---------------------------------------------------------------------------
__global__ __launch_bounds__(1024) void wkv_scan_par(
    const unsigned short* __restrict__ rkv,
    const float* __restrict__ td,  const float* __restrict__ tf,
    const float* __restrict__ tdr, const float* __restrict__ tfr,
    unsigned short* __restrict__ outcat)
{
    __shared__ float sBn[SEG][CHB], sBd[SEG][CHB], sMb[SEG][CHB];

    const int tid = threadIdx.x;
    const int ch  = tid & (CHB - 1);
    const int seg = tid >> 5;

    const int bi  = blockIdx.x;
    const int b   = bi >> 6;
    const int rem = bi & 63;
    const int dir = rem >> 5;
    const int c   = (rem & 31) * CHB + ch;

    const float w = -__expf(dir ? tdr[c] : td[c]);
    const float u = dir ? tfr[c] : tf[c];

    const int strideT = 6 * Cdim;
    const int tstep   = dir ? -strideT : strideT;
    const int t0      = dir ? (Tdim - 1 - seg * LSEG) : (seg * LSEG);

    const unsigned short* pbase = rkv + ((size_t)b * Tdim + t0) * strideT + dir * 3 * Cdim + c;

    const int PF = 8;

    float bn = 0.0f, bd = 0.0f, mb = -1e38f;
    {
        const unsigned short* q = pbase;
        float kk[PF], vv[PF];
        #pragma unroll
        for (int i = 0; i < PF; ++i) {
            kk[i] = bf2f(q[Cdim]); vv[i] = bf2f(q[2 * Cdim]); q += tstep;
        }
        for (int t = 0; t < LSEG; t += PF) {
            float kn[PF], vn[PF];
            if (t + PF < LSEG) {
                #pragma unroll
                for (int i = 0; i < PF; ++i) {
                    kn[i] = bf2f(q[Cdim]); vn[i] = bf2f(q[2 * Cdim]); q += tstep;
                }
            }
            #pragma unroll
            for (int i = 0; i < PF; ++i) {
                const float k_ = kk[i], v_ = vv[i];
                const float mw = mb + w;
                const float mn = fmaxf(mw, k_);
                const float e1 = __expf(mw - mn);
                const float e2 = __expf(k_ - mn);
                bn = e1 * bn + e2 * v_;
                bd = e1 * bd + e2;
                mb = mn;
            }
            #pragma unroll
            for (int i = 0; i < PF; ++i) { kk[i] = kn[i]; vv[i] = vn[i]; }
        }
    }
    sBn[seg][ch] = bn; sBd[seg][ch] = bd; sMb[seg][ch] = mb;
    __syncthreads();

    if (tid < CHB) {
        float n = 0.0f, d = 0.0f, m = -1e38f;
        const float a = w * (float)LSEG;
        for (int s = 0; s < SEG; ++s) {
            const float tn = sBn[s][tid], tdn = sBd[s][tid], tm = sMb[s][tid];
            sBn[s][tid] = n; sBd[s][tid] = d; sMb[s][tid] = m;
            const float ma = m + a;
            const float mm = fmaxf(ma, tm);
            const float e1 = __expf(ma - mm);
            const float e2 = __expf(tm - mm);
            n = e1 * n + e2 * tn;
            d = e1 * d + e2 * tdn;
            m = mm;
        }
    }
    __syncthreads();

    float num = sBn[seg][ch], den = sBd[seg][ch], mx = sMb[seg][ch];
    {
        const unsigned short* q = pbase;
        unsigned short* po = outcat + ((size_t)b * Tdim + t0) * (2 * Cdim) + dir * Cdim + c;
        const int ostep = dir ? -(2 * Cdim) : (2 * Cdim);

        float rr[PF], kk[PF], vv[PF];
        #pragma unroll
        for (int i = 0; i < PF; ++i) {
            rr[i] = bf2f(q[0]); kk[i] = bf2f(q[Cdim]); vv[i] = bf2f(q[2 * Cdim]); q += tstep;
        }
        for (int t = 0; t < LSEG; t += PF) {
            float rn[PF], kn[PF], vn[PF];
            if (t + PF < LSEG) {
                #pragma unroll
                for (int i = 0; i < PF; ++i) {
                    rn[i] = bf2f(q[0]); kn[i] = bf2f(q[Cdim]); vn[i] = bf2f(q[2 * Cdim]); q += tstep;
                }
            }
            #pragma unroll
            for (int i = 0; i < PF; ++i) {
                const float k_ = kk[i], v_ = vv[i], r_ = rr[i];
                const float ku = k_ + u;
                const float m  = fmaxf(mx, ku);
                const float e1 = __expf(mx - m);
                const float e2 = __expf(ku - m);
                const float y  = (e1 * num + e2 * v_) / (e1 * den + e2);
                const float sr = 1.0f / (1.0f + __expf(-r_));
                *po = f2bf(sr * y);
                po += ostep;
                const float mw  = mx + w;
                const float mn  = fmaxf(mw, k_);
                const float e1s = __expf(mw - mn);
                const float e2s = __expf(k_ - mn);
                num = e1s * num + e2s * v_;
                den = e1s * den + e2s;
                mx  = mn;
            }
            #pragma unroll
            for (int i = 0; i < PF; ++i) { rr[i] = rn[i]; kk[i] = kn[i]; vv[i] = vn[i]; }
        }
    }
}

// ---------------------------------------------------------------------------
extern "C" void kernel_launch(void* const* d_in, const int* in_sizes, int n_in,
                              void* d_out, int out_size, void* d_ws, size_t ws_size,
                              hipStream_t stream)
{
    const float* x    = (const float*)d_in[0];
    const float* rkvw = (const float*)d_in[1];
    const float* outw = (const float*)d_in[2];
    const float* td   = (const float*)d_in[3];
    const float* tf   = (const float*)d_in[4];
    const float* tdr  = (const float*)d_in[5];
    const float* tfr  = (const float*)d_in[6];
    float* out = (float*)d_out;

    const int M = Bdim * Tdim;   // 8192

    char* ws = (char*)d_ws;
    unsigned short* rkv = (unsigned short*)ws;                 //  96 MiB bf16 [B,T,6C]
    unsigned short* xb  = (unsigned short*)(ws + 100663296);   //  16 MiB bf16 x
    unsigned short* wb  = (unsigned short*)(ws + 117440512);   //  12 MiB bf16 rkv_w
    unsigned short* ob  = (unsigned short*)(ws + 130023424);   //   4 MiB bf16 out_w
    unsigned short* cat = (unsigned short*)(ws + 134217728);   //  32 MiB bf16 out_cat

    const int n1 = M * Cdim / 4;              // x quads
    const int n2 = 6 * Cdim * Cdim / 4;       // rkv_w quads
    const int n3 = Cdim * 2 * Cdim / 4;       // out_w quads

    // merged casts (one launch)
    hipLaunchKernelGGL(cast_all, dim3((n1 + n2 + n3 + 255) / 256), dim3(256), 0, stream,
                       x, xb, n1, rkvw, wb, n2, outw, ob, n3);

    // GEMM1: 256x128 tile, 3-slot, 2 blocks/CU; grid 1536
    hipLaunchKernelGGL(gemm1_3slot, dim3(G1_NWG), dim3(512), 0, stream, xb, wb, rkv);

    // segmented-parallel fused sigmoid + bidirectional WKV scan
    hipLaunchKernelGGL(wkv_scan_par, dim3(Bdim * 2 * (Cdim / CHB)), dim3(1024), 0, stream,
                       rkv, td, tf, tdr, tfr, cat);

    // GEMM2 (m97 128², fp32 out): M=8192, N=1024, K=2048; grid 8x64=512
    hipLaunchKernelGGL(gemm_bf16_nt, dim3(Cdim / 128, M / 128), dim3(256), 0, stream,
                       cat, ob, out, M, Cdim, 2 * Cdim);
}